// Round 6
// baseline (1236.191 us; speedup 1.0000x reference)
//
#include <hip/hip_runtime.h>

typedef unsigned short u16;
typedef __bf16 bf16x8 __attribute__((ext_vector_type(8)));
typedef float f32x4 __attribute__((ext_vector_type(4)));

#define TOKENS 200704
#define QK_ELEMS 51380224UL   // 32768 pairs * 49 * 32 (each of Q,K,V)

__device__ __forceinline__ u16 f2b(float f) {
    __bf16 h = (__bf16)f;                 // hw v_cvt (RTNE)
    return __builtin_bit_cast(u16, h);
}

#define GLDS(g, l) __builtin_amdgcn_global_load_lds( \
    (const __attribute__((address_space(1))) void*)(g), \
    (__attribute__((address_space(3))) void*)(l), 16, 0, 0)

// ---------------------------------------------------------------------------
// GEMM: C[m,n] = sum_k A[m,k] * W[n,k]  (A bf16 MxK row-major, W bf16 NxK row-major)
// 128x128 tile, BK=64, 256 threads (4 waves, 2x2), each wave 64x64 (4x4 frags).
// 2-PHASE double-buffered pipeline (T3 minimum recipe): issue STAGE(t+1) before
// compute(t); single __syncthreads() per K-step (vmcnt drain overlaps MFMA).
// LDS XOR-swizzle: linear global_load_lds dest + pre-swizzled global source col
// + XOR on the ds_read side (conflict-free).
// EPI 0: qkv (+bias, q pre-scaled) -> (pair*49+pos)*32+d layout for Q,K,V
// EPI 1: proj (+bias +x residual -> f32 out)
// EPI 2: fc1 (+bias, fast GELU -> bf16)      EPI 3: fc2 (+bias, out += )
// ---------------------------------------------------------------------------
template<int EPI>
__global__ __launch_bounds__(256)
void gemm_bt(const u16* __restrict__ A, const u16* __restrict__ W,
             const float* __restrict__ bias, int nt, int K,
             u16* __restrict__ outb, float* __restrict__ outf,
             const float* __restrict__ res)
{
    __shared__ u16 As[2][128 * 64];
    __shared__ u16 Bs[2][128 * 64];
    const int tid  = threadIdx.x;
    const int wave = tid >> 6, lane = tid & 63;

    // bijective XCD-aware block swizzle (m204): contiguous chunk per XCD
    const int nwg = gridDim.x, bidO = blockIdx.x;
    const int qq = nwg >> 3, rr = nwg & 7;
    const int xcd = bidO & 7, idxx = bidO >> 3;
    const int bid = (xcd < rr) ? (xcd * (qq + 1) + idxx)
                               : (rr * (qq + 1) + (xcd - rr) * qq + idxx);

    const int bm = bid / nt, bn = bid % nt;
    const long m0 = (long)bm * 128;
    const int  n0 = bn * 128;
    const int wm = (wave >> 1) * 64, wn = (wave & 1) * 64;
    const int lr = lane & 15, lg = lane >> 4;
    const int crow   = lane >> 3;                       // row within 8-row chunk
    const int ccol_s = ((lane & 7) ^ crow) * 8;         // swizzled global col

    f32x4 acc[4][4] = {};

    auto stage = [&](int buf, int k0) {
#pragma unroll
        for (int p = 0; p < 4; ++p) {
            const int i = wave * 4 + p;          // chunk 0..15 (wave-uniform)
            const int row = i * 8 + crow;
            GLDS(A + (m0 + row) * (long)K + k0 + ccol_s, &As[buf][i * 512]);
            GLDS(W + (long)(n0 + row) * K + k0 + ccol_s, &Bs[buf][i * 512]);
        }
    };
    auto compute = [&](int buf) {
#pragma unroll
        for (int kk = 0; kk < 64; kk += 32) {
            bf16x8 af[4], bfr[4];
            const int swz = (lr & 7) * 8;
#pragma unroll
            for (int fm = 0; fm < 4; ++fm)
                af[fm] = *reinterpret_cast<const bf16x8*>(
                    &As[buf][(wm + fm * 16 + lr) * 64 + ((kk + lg * 8) ^ swz)]);
#pragma unroll
            for (int fn = 0; fn < 4; ++fn)
                bfr[fn] = *reinterpret_cast<const bf16x8*>(
                    &Bs[buf][(wn + fn * 16 + lr) * 64 + ((kk + lg * 8) ^ swz)]);
#pragma unroll
            for (int fm = 0; fm < 4; ++fm)
#pragma unroll
                for (int fn = 0; fn < 4; ++fn)
                    acc[fm][fn] = __builtin_amdgcn_mfma_f32_16x16x32_bf16(af[fm], bfr[fn], acc[fm][fn], 0, 0, 0);
        }
    };

    const int nk = K >> 6;                      // K-tiles (4 or 16, always even)
    stage(0, 0);
    __syncthreads();
    int k = 64;
    for (int t = 0; t < nk - 2; t += 2) {
        stage(1, k); compute(0); __syncthreads(); k += 64;
        stage(0, k); compute(1); __syncthreads(); k += 64;
    }
    stage(1, k); compute(0); __syncthreads();
    compute(1);

#pragma unroll
    for (int fm = 0; fm < 4; ++fm) {
#pragma unroll
        for (int r = 0; r < 4; ++r) {
            const long m = m0 + wm + fm * 16 + lg * 4 + r;
            size_t mpart = 0;
            if (EPI == 0) {                    // hoisted m-decomposition
                const int mm = (int)m;
                const int b = mm / 50176;
                const int rem = mm % 50176;
                const int y = rem / 224, x = rem % 224;
                const int win = (b * 32 + y / 7) * 32 + x / 7;
                const int pos = (y % 7) * 7 + (x % 7);
                mpart = (size_t)win * 12544 + (size_t)pos * 32;
            }
#pragma unroll
            for (int fn = 0; fn < 4; ++fn) {
                const int n = n0 + wn + fn * 16 + lr;
                const float v = acc[fm][fn][r];
                if (EPI == 0) {
                    const int sec = n >> 8, hd = (n >> 5) & 7, d = n & 31;
                    const float sc = (sec == 0) ? 0.17677669529663687f : 1.0f;
                    outb[sec * QK_ELEMS + mpart + hd * 1568 + d] = f2b((v + bias[n]) * sc);
                } else if (EPI == 1) {
                    outf[m * 256 + n] = v + bias[n] + res[m * 256 + n];
                } else if (EPI == 2) {
                    const float t = v + bias[n];
                    // tanh-approx GELU: t * sigmoid(1.59577*(t + 0.044715 t^3))
                    const float s = t * (1.5957691216f + 0.07135481627f * t * t);
                    const float g = t * __builtin_amdgcn_rcpf(1.0f + __expf(-s));
                    outb[m * 1024 + n] = f2b(g);
                } else {
                    outf[m * 256 + n] += v + bias[n];
                }
            }
        }
    }
}

// ---------------------------------------------------------------------------
// LayerNorm over C=256, f32 in -> bf16 out. 1 wave per token, 4 tokens/block.
// ---------------------------------------------------------------------------
__global__ __launch_bounds__(256)
void layernorm_k(const float* __restrict__ in, const float* __restrict__ g,
                 const float* __restrict__ bb, u16* __restrict__ out)
{
    const int token = blockIdx.x * 4 + (threadIdx.x >> 6);
    const int lane = threadIdx.x & 63;
    const float4 v = *reinterpret_cast<const float4*>(in + (size_t)token * 256 + lane * 4);
    float s  = v.x + v.y + v.z + v.w;
    float s2 = v.x * v.x + v.y * v.y + v.z * v.z + v.w * v.w;
#pragma unroll
    for (int m = 1; m < 64; m <<= 1) { s += __shfl_xor(s, m); s2 += __shfl_xor(s2, m); }
    const float mu  = s * (1.0f / 256.0f);
    const float var = s2 * (1.0f / 256.0f) - mu * mu;
    const float rs  = rsqrtf(var + 1e-5f);
    const float4 gv = *reinterpret_cast<const float4*>(g + lane * 4);
    const float4 bv = *reinterpret_cast<const float4*>(bb + lane * 4);
    ushort4 o;
    o.x = f2b((v.x - mu) * rs * gv.x + bv.x);
    o.y = f2b((v.y - mu) * rs * gv.y + bv.y);
    o.z = f2b((v.z - mu) * rs * gv.z + bv.z);
    o.w = f2b((v.w - mu) * rs * gv.w + bv.w);
    *reinterpret_cast<ushort4*>(out + (size_t)token * 256 + lane * 4) = o;
}

// ---------------------------------------------------------------------------
// Window attention: 1 wave per (window, head). Q pre-scaled. N=49 padded to 64.
// V arrives row-major [pos][d]; transposed per-wave through LDS into [d][pos]
// (pitch 72 u16 = 144 B -> ds_read_b128 conflict-free).
// ---------------------------------------------------------------------------
__global__ __launch_bounds__(256)
void attn_win(const u16* __restrict__ qkv, const float* __restrict__ biasF,
              u16* __restrict__ outb)
{
    __shared__ u16 plds[4][64 * 72];
    __shared__ u16 vlds[4][32 * 72];
    const int wave = threadIdx.x >> 6, lane = threadIdx.x & 63;
    const int pair = blockIdx.x * 4 + wave;
    const int head = pair & 7, win = pair >> 3;
    const int lr = lane & 15, lg = lane >> 4;

    const u16* Q  = qkv + (size_t)pair * 1568;
    const u16* Kp = qkv + QK_ELEMS + (size_t)pair * 1568;
    const u16* Vp = qkv + 2 * QK_ELEMS + (size_t)pair * 1568;

    // ---- stage V^T into LDS (zero the pad columns pos=49..63 first) ----
    u16* vl = &vlds[wave][0];
#pragma unroll
    for (int it = 0; it < 8; ++it) {
        const int idx = it * 64 + lane;            // 480 pad elems: 32 d x 15 pos
        if (idx < 480) vl[(idx / 15) * 72 + 49 + idx % 15] = 0;
    }
#pragma unroll
    for (int it = 0; it < 4; ++it) {
        const int idx = it * 64 + lane;            // 196 groups of 8 elems
        if (idx < 196) {
            const int pos = idx >> 2, dc = idx & 3;
            const uint4 vv = *reinterpret_cast<const uint4*>(Vp + pos * 32 + dc * 8);
            u16* dst = vl + (dc * 8) * 72 + pos;
            dst[0 * 72] = (u16)vv.x;  dst[1 * 72] = (u16)(vv.x >> 16);
            dst[2 * 72] = (u16)vv.y;  dst[3 * 72] = (u16)(vv.y >> 16);
            dst[4 * 72] = (u16)vv.z;  dst[5 * 72] = (u16)(vv.z >> 16);
            dst[6 * 72] = (u16)vv.w;  dst[7 * 72] = (u16)(vv.w >> 16);
        }
    }

    // ---- QK^T ----
    bf16x8 qf[4], kf[4];
#pragma unroll
    for (int f = 0; f < 4; ++f) {
        int n = f * 16 + lr; n = n > 48 ? 48 : n;
        qf[f] = *reinterpret_cast<const bf16x8*>(Q  + n * 32 + lg * 8);
        kf[f] = *reinterpret_cast<const bf16x8*>(Kp + n * 32 + lg * 8);
    }
    f32x4 s[4][4] = {};
#pragma unroll
    for (int fm = 0; fm < 4; ++fm)
#pragma unroll
        for (int fn = 0; fn < 4; ++fn)
            s[fm][fn] = __builtin_amdgcn_mfma_f32_16x16x32_bf16(qf[fm], kf[fn], s[fm][fn], 0, 0, 0);

    // ---- softmax (wave-parallel, 16-lane-group reduce) ----
    const float* bh = biasF + head * 2401;
    u16* pl = &plds[wave][0];
#pragma unroll
    for (int fm = 0; fm < 4; ++fm) {
#pragma unroll
        for (int r = 0; r < 4; ++r) {
            const int row = fm * 16 + lg * 4 + r;
            const int brow = row > 48 ? 48 : row;
            float v[4];
#pragma unroll
            for (int fn = 0; fn < 4; ++fn) {
                const int col = fn * 16 + lr;
                const float bval = bh[brow * 49 + (col > 48 ? 48 : col)];
                v[fn] = (col > 48) ? -3.0e38f : (s[fm][fn][r] + bval);
            }
            float mx = fmaxf(fmaxf(v[0], v[1]), fmaxf(v[2], v[3]));
#pragma unroll
            for (int d = 1; d < 16; d <<= 1) mx = fmaxf(mx, __shfl_xor(mx, d));
            float p[4], sum = 0.f;
#pragma unroll
            for (int fn = 0; fn < 4; ++fn) {
                const int col = fn * 16 + lr;
                p[fn] = (col <= 48) ? __expf(v[fn] - mx) : 0.f;
                sum += p[fn];
            }
#pragma unroll
            for (int d = 1; d < 16; d <<= 1) sum += __shfl_xor(sum, d);
            const float rinv = __builtin_amdgcn_rcpf(sum);
#pragma unroll
            for (int fn = 0; fn < 4; ++fn)
                pl[row * 72 + fn * 16 + lr] = f2b(p[fn] * rinv);
        }
    }
    __syncthreads();

    // ---- PV ----
    f32x4 o[4][2] = {};
#pragma unroll
    for (int kc = 0; kc < 2; ++kc) {
        bf16x8 vf[2];
#pragma unroll
        for (int f2 = 0; f2 < 2; ++f2)
            vf[f2] = *reinterpret_cast<const bf16x8*>(vl + (f2 * 16 + lr) * 72 + kc * 32 + lg * 8);
#pragma unroll
        for (int fm = 0; fm < 4; ++fm) {
            const bf16x8 pa = *reinterpret_cast<const bf16x8*>(pl + (fm * 16 + lr) * 72 + kc * 32 + lg * 8);
#pragma unroll
            for (int f2 = 0; f2 < 2; ++f2)
                o[fm][f2] = __builtin_amdgcn_mfma_f32_16x16x32_bf16(pa, vf[f2], o[fm][f2], 0, 0, 0);
        }
    }

    // ---- window-reverse store ----
    const int b = win >> 10, rem = win & 1023, wy = rem >> 5, wx = rem & 31;
#pragma unroll
    for (int fm = 0; fm < 4; ++fm) {
#pragma unroll
        for (int r = 0; r < 4; ++r) {
            const int tok = fm * 16 + lg * 4 + r;
            if (tok > 48) continue;
            const int y = wy * 7 + tok / 7, xx = wx * 7 + tok % 7;
            const size_t mrow = ((size_t)(b * 224 + y)) * 224 + xx;
#pragma unroll
            for (int f2 = 0; f2 < 2; ++f2)
                outb[mrow * 256 + head * 32 + f2 * 16 + lr] = f2b(o[fm][f2][r]);
        }
    }
}

// ---------------------------------------------------------------------------
// Helpers
// ---------------------------------------------------------------------------
__global__ __launch_bounds__(256)
void cvt_w(const float* __restrict__ qw, const float* __restrict__ pw,
           const float* __restrict__ f1, const float* __restrict__ f2,
           u16* __restrict__ outw)
{
    const int t = blockIdx.x * 256 + threadIdx.x;  // 786432 total
    float v;
    if (t < 196608) v = qw[t];
    else if (t < 262144) v = pw[t - 196608];
    else if (t < 524288) v = f1[t - 262144];
    else v = f2[t - 524288];
    outw[t] = f2b(v);
}

__global__ __launch_bounds__(256)
void bias_pre(const float* __restrict__ btab, const int* __restrict__ relidx,
              float* __restrict__ biasF)
{
    const int t = blockIdx.x * 256 + threadIdx.x;
    if (t >= 19208) return;
    const int head = t / 2401, ij = t % 2401;
    biasF[t] = btab[relidx[ij] * 8 + head];
}

// ---------------------------------------------------------------------------
extern "C" void kernel_launch(void* const* d_in, const int* in_sizes, int n_in,
                              void* d_out, int out_size, void* d_ws, size_t ws_size,
                              hipStream_t stream)
{
    const float* x      = (const float*)d_in[0];
    const float* n1g    = (const float*)d_in[1];
    const float* n1b    = (const float*)d_in[2];
    const float* qkv_w  = (const float*)d_in[3];
    const float* qkv_b  = (const float*)d_in[4];
    const float* btab   = (const float*)d_in[5];
    const float* proj_w = (const float*)d_in[6];
    const float* proj_b = (const float*)d_in[7];
    const float* n2g    = (const float*)d_in[8];
    const float* n2b    = (const float*)d_in[9];
    const float* fc1_w  = (const float*)d_in[10];
    const float* fc1_b  = (const float*)d_in[11];
    const float* fc2_w  = (const float*)d_in[12];
    const float* fc2_b  = (const float*)d_in[13];
    const int*   relidx = (const int*)d_in[14];
    float* out = (float*)d_out;

    // workspace layout:
    //  [0, 1572864)                    : bf16 weights
    //  [1572864, 1649696)              : bias_full f32 (8x49x49)
    //  [1650688, +102760448)           : A region (bf16 token x 256): h / attn_out / h2
    //  [104411136, ...)                : R region: Q|K|V (308.3 MB), reused as MLP hidden
    char* ws = (char*)d_ws;
    u16*   wbf   = (u16*)ws;
    float* biasF = (float*)(ws + 1572864);
    u16*   hbuf  = (u16*)(ws + 1650688);
    u16*   rbuf  = (u16*)(ws + 1650688 + 102760448);
    const size_t r_avail = ws_size - (1650688 + 102760448);

    const u16* Wq  = wbf;
    const u16* Wp  = wbf + 196608;
    const u16* Wf1 = wbf + 262144;
    const u16* Wf2 = wbf + 524288;

    cvt_w<<<3072, 256, 0, stream>>>(qkv_w, proj_w, fc1_w, fc2_w, wbf);
    bias_pre<<<76, 256, 0, stream>>>(btab, relidx, biasF);
    layernorm_k<<<50176, 256, 0, stream>>>(x, n1g, n1b, hbuf);

    // QKV projection: M=200704, N=768, K=256
    gemm_bt<0><<<1568 * 6, 256, 0, stream>>>(hbuf, Wq, qkv_b, 6, 256, rbuf, nullptr, nullptr);
    // window attention
    attn_win<<<8192, 256, 0, stream>>>(rbuf, biasF, hbuf);
    // proj + residual -> d_out (x1)
    gemm_bt<1><<<1568 * 2, 256, 0, stream>>>(hbuf, Wp, proj_b, 2, 256, nullptr, out, x);
    // LN2: d_out -> h2
    layernorm_k<<<50176, 256, 0, stream>>>(out, n2g, n2b, hbuf);

    // MLP, chunked so hidden (bf16, M x 1024) fits in R region
    long rows_cap = (long)(r_avail / 2048);
    long rows_per = (rows_cap / 128) * 128;
    if (rows_per > TOKENS) rows_per = TOKENS;
    if (rows_per < 128) rows_per = 128;
    for (long r0 = 0; r0 < TOKENS; r0 += rows_per) {
        const long rows = (TOKENS - r0 < rows_per) ? (TOKENS - r0) : rows_per;
        gemm_bt<2><<<(int)((rows / 128) * 8), 256, 0, stream>>>(
            hbuf + r0 * 256, Wf1, fc1_b, 8, 256, rbuf, nullptr, nullptr);
        gemm_bt<3><<<(int)((rows / 128) * 2), 256, 0, stream>>>(
            rbuf, Wf2, fc2_b, 2, 1024, nullptr, out + r0 * 256, nullptr);
    }
}

// Round 7
// 1134.581 us; speedup vs baseline: 1.0896x; 1.0896x over previous
//
#include <hip/hip_runtime.h>

typedef unsigned short u16;
typedef __bf16 bf16x8 __attribute__((ext_vector_type(8)));
typedef float f32x4 __attribute__((ext_vector_type(4)));

#define TOKENS 200704
#define QK_ELEMS 51380224UL   // 32768 pairs * 49 * 32 (each of Q,K,V)

__device__ __forceinline__ u16 f2b(float f) {
    __bf16 h = (__bf16)f;                 // hw v_cvt (RTNE)
    return __builtin_bit_cast(u16, h);
}

#define GLDS(g, l) __builtin_amdgcn_global_load_lds( \
    (const __attribute__((address_space(1))) void*)(g), \
    (__attribute__((address_space(3))) void*)(l), 16, 0, 0)

#define MFMA __builtin_amdgcn_mfma_f32_16x16x32_bf16

// ---------------------------------------------------------------------------
// GEMM: C[m,n] = sum_k A[m,k]*W[n,k].  256x256 tile, BK=64, 512 thr (8 waves
// 2Mx4N, each wave 128x64 out = 8x4 16x16 frags). Double-buffered 128 KB LDS.
// Counted-vmcnt pipeline (T3/T4): raw s_barrier; vmcnt(8) gate keeps next
// tile's 8 global_load_lds in flight across barriers; stage(t+2) issued right
// after the done-barrier. setprio(1) around each 16-MFMA quadrant (T5).
// LDS XOR-swizzle (conflict-free, verified 0 conflicts in R4-R6): linear GLDS
// dest + pre-swizzled global source col + XOR on ds_read.
// EPI 0: qkv (+bias, q pre-scaled) -> (pair*49+pos)*32+d for Q,K,V
// EPI 1: proj (+bias +x residual -> f32) EPI 2: fc1 (+bias,GELU -> bf16)
// EPI 3: fc2 (+bias, out +=)
// ---------------------------------------------------------------------------
template<int EPI>
__global__ __launch_bounds__(512, 2)
void gemm256(const u16* __restrict__ A, const u16* __restrict__ W,
             const float* __restrict__ bias, int nt, int K,
             u16* __restrict__ outb, float* __restrict__ outf,
             const float* __restrict__ res)
{
    __shared__ u16 As[2][256 * 64];
    __shared__ u16 Bs[2][256 * 64];
    const int tid  = threadIdx.x;
    const int wave = tid >> 6, lane = tid & 63;

    // bijective XCD-aware block swizzle (m204)
    const int nwg = gridDim.x, bidO = blockIdx.x;
    const int qq = nwg >> 3, rr = nwg & 7;
    const int xcd = bidO & 7, idxx = bidO >> 3;
    const int bid = (xcd < rr) ? (xcd * (qq + 1) + idxx)
                               : (rr * (qq + 1) + (xcd - rr) * qq + idxx);

    const int bm = bid / nt, bn = bid % nt;
    const long m0 = (long)bm * 256;
    const int  n0 = bn * 256;
    const int wr = wave >> 2, wc = wave & 3;      // 2 x 4 wave grid
    const int lr = lane & 15, lg = lane >> 4;
    const int crow   = lane >> 3;
    const int ccol_s = ((lane & 7) ^ crow) * 8;   // swizzled global col
    const int swz    = (lr & 7) * 8;

    f32x4 acc[8][4] = {};

    auto stage = [&](int buf, int k0) {
#pragma unroll
        for (int p = 0; p < 4; ++p) {
            const int i = p * 8 + wave;           // chunk 0..31 (8 rows each)
            const int row = i * 8 + crow;
            GLDS(A + (m0 + row) * (long)K + k0 + ccol_s, &As[buf][i * 512]);
            GLDS(W + (long)(n0 + row) * K + k0 + ccol_s, &Bs[buf][i * 512]);
        }
    };

    auto compute = [&](int buf) {
        bf16x8 bfr[2][4];                          // [kk][fn], constant-indexed
#pragma unroll
        for (int kk2 = 0; kk2 < 2; ++kk2)
#pragma unroll
            for (int fn = 0; fn < 4; ++fn)
                bfr[kk2][fn] = *reinterpret_cast<const bf16x8*>(
                    &Bs[buf][(wc * 64 + fn * 16 + lr) * 64 + ((kk2 * 32 + lg * 8) ^ swz)]);
        bf16x8 aq[2][2], an[2][2];                 // quadrant double-buffer [fmpar][kk]
#pragma unroll
        for (int p = 0; p < 2; ++p)
#pragma unroll
            for (int kk2 = 0; kk2 < 2; ++kk2)
                aq[p][kk2] = *reinterpret_cast<const bf16x8*>(
                    &As[buf][(wr * 128 + p * 16 + lr) * 64 + ((kk2 * 32 + lg * 8) ^ swz)]);
#pragma unroll
        for (int q = 0; q < 4; ++q) {
            bf16x8 (&cur)[2][2] = (q & 1) ? an : aq;
            bf16x8 (&nxt)[2][2] = (q & 1) ? aq : an;
            if (q < 3) {
#pragma unroll
                for (int p = 0; p < 2; ++p)
#pragma unroll
                    for (int kk2 = 0; kk2 < 2; ++kk2)
                        nxt[p][kk2] = *reinterpret_cast<const bf16x8*>(
                            &As[buf][(wr * 128 + (2 * (q + 1) + p) * 16 + lr) * 64 + ((kk2 * 32 + lg * 8) ^ swz)]);
            }
            __builtin_amdgcn_s_setprio(1);
#pragma unroll
            for (int p = 0; p < 2; ++p)
#pragma unroll
                for (int kk2 = 0; kk2 < 2; ++kk2)
#pragma unroll
                    for (int fn = 0; fn < 4; ++fn)
                        acc[2 * q + p][fn] = MFMA(cur[p][kk2], bfr[kk2][fn], acc[2 * q + p][fn], 0, 0, 0);
            __builtin_amdgcn_s_setprio(0);
        }
    };

    const int nk = K >> 6;                        // 4 or 16
    stage(0, 0);
    stage(1, 64);
    int k = 128;
    for (int t = 0; t < nk - 1; ++t) {
        asm volatile("s_waitcnt vmcnt(8)" ::: "memory");   // tile t landed (t+1's 8 younger)
        __builtin_amdgcn_s_barrier();
        __builtin_amdgcn_sched_barrier(0);
        compute(t & 1);
        __builtin_amdgcn_s_barrier();                       // all waves done reading buf t&1
        __builtin_amdgcn_sched_barrier(0);
        if (t + 2 < nk) {
            stage(t & 1, k); k += 64;
            __builtin_amdgcn_sched_barrier(0);
        }
    }
    asm volatile("s_waitcnt vmcnt(0)" ::: "memory");
    __builtin_amdgcn_s_barrier();
    __builtin_amdgcn_sched_barrier(0);
    compute((nk - 1) & 1);

#pragma unroll
    for (int fm = 0; fm < 8; ++fm) {
#pragma unroll
        for (int r = 0; r < 4; ++r) {
            const long m = m0 + wr * 128 + fm * 16 + lg * 4 + r;
            size_t mpart = 0;
            if (EPI == 0) {                       // hoisted m-decomposition
                const int mm = (int)m;
                const int b = mm / 50176;
                const int rem = mm % 50176;
                const int y = rem / 224, x = rem % 224;
                const int win = (b * 32 + y / 7) * 32 + x / 7;
                const int pos = (y % 7) * 7 + (x % 7);
                mpart = (size_t)win * 12544 + (size_t)pos * 32;
            }
#pragma unroll
            for (int fn = 0; fn < 4; ++fn) {
                const int n = n0 + wc * 64 + fn * 16 + lr;
                const float v = acc[fm][fn][r];
                if (EPI == 0) {
                    const int sec = n >> 8, hd = (n >> 5) & 7, d = n & 31;
                    const float sc = (sec == 0) ? 0.17677669529663687f : 1.0f;
                    outb[sec * QK_ELEMS + mpart + hd * 1568 + d] = f2b((v + bias[n]) * sc);
                } else if (EPI == 1) {
                    outf[m * 256 + n] = v + bias[n] + res[m * 256 + n];
                } else if (EPI == 2) {
                    const float t = v + bias[n];
                    const float s = t * (1.5957691216f + 0.07135481627f * t * t);
                    const float g = t * __builtin_amdgcn_rcpf(1.0f + __expf(-s));
                    outb[m * 1024 + n] = f2b(g);
                } else {
                    outf[m * 256 + n] += v + bias[n];
                }
            }
        }
    }
}

// ---------------------------------------------------------------------------
// LayerNorm over C=256, f32 in -> bf16 out. 1 wave per token, 4 tokens/block.
// ---------------------------------------------------------------------------
__global__ __launch_bounds__(256)
void layernorm_k(const float* __restrict__ in, const float* __restrict__ g,
                 const float* __restrict__ bb, u16* __restrict__ out)
{
    const int token = blockIdx.x * 4 + (threadIdx.x >> 6);
    const int lane = threadIdx.x & 63;
    const float4 v = *reinterpret_cast<const float4*>(in + (size_t)token * 256 + lane * 4);
    float s  = v.x + v.y + v.z + v.w;
    float s2 = v.x * v.x + v.y * v.y + v.z * v.z + v.w * v.w;
#pragma unroll
    for (int m = 1; m < 64; m <<= 1) { s += __shfl_xor(s, m); s2 += __shfl_xor(s2, m); }
    const float mu  = s * (1.0f / 256.0f);
    const float var = s2 * (1.0f / 256.0f) - mu * mu;
    const float rs  = rsqrtf(var + 1e-5f);
    const float4 gv = *reinterpret_cast<const float4*>(g + lane * 4);
    const float4 bv = *reinterpret_cast<const float4*>(bb + lane * 4);
    ushort4 o;
    o.x = f2b((v.x - mu) * rs * gv.x + bv.x);
    o.y = f2b((v.y - mu) * rs * gv.y + bv.y);
    o.z = f2b((v.z - mu) * rs * gv.z + bv.z);
    o.w = f2b((v.w - mu) * rs * gv.w + bv.w);
    *reinterpret_cast<ushort4*>(out + (size_t)token * 256 + lane * 4) = o;
}

// ---------------------------------------------------------------------------
// Window attention: 1 wave per (window, head). Q pre-scaled. N=49 padded to 64.
// ---------------------------------------------------------------------------
__global__ __launch_bounds__(256)
void attn_win(const u16* __restrict__ qkv, const float* __restrict__ biasF,
              u16* __restrict__ outb)
{
    __shared__ u16 plds[4][64 * 72];
    __shared__ u16 vlds[4][32 * 72];
    const int wave = threadIdx.x >> 6, lane = threadIdx.x & 63;
    const int pair = blockIdx.x * 4 + wave;
    const int head = pair & 7, win = pair >> 3;
    const int lr = lane & 15, lg = lane >> 4;

    const u16* Q  = qkv + (size_t)pair * 1568;
    const u16* Kp = qkv + QK_ELEMS + (size_t)pair * 1568;
    const u16* Vp = qkv + 2 * QK_ELEMS + (size_t)pair * 1568;

    // ---- stage V^T into LDS (zero the pad columns pos=49..63 first) ----
    u16* vl = &vlds[wave][0];
#pragma unroll
    for (int it = 0; it < 8; ++it) {
        const int idx = it * 64 + lane;            // 480 pad elems: 32 d x 15 pos
        if (idx < 480) vl[(idx / 15) * 72 + 49 + idx % 15] = 0;
    }
#pragma unroll
    for (int it = 0; it < 4; ++it) {
        const int idx = it * 64 + lane;            // 196 groups of 8 elems
        if (idx < 196) {
            const int pos = idx >> 2, dc = idx & 3;
            const uint4 vv = *reinterpret_cast<const uint4*>(Vp + pos * 32 + dc * 8);
            u16* dst = vl + (dc * 8) * 72 + pos;
            dst[0 * 72] = (u16)vv.x;  dst[1 * 72] = (u16)(vv.x >> 16);
            dst[2 * 72] = (u16)vv.y;  dst[3 * 72] = (u16)(vv.y >> 16);
            dst[4 * 72] = (u16)vv.z;  dst[5 * 72] = (u16)(vv.z >> 16);
            dst[6 * 72] = (u16)vv.w;  dst[7 * 72] = (u16)(vv.w >> 16);
        }
    }

    // ---- QK^T ----
    bf16x8 qf[4], kf[4];
#pragma unroll
    for (int f = 0; f < 4; ++f) {
        int n = f * 16 + lr; n = n > 48 ? 48 : n;
        qf[f] = *reinterpret_cast<const bf16x8*>(Q  + n * 32 + lg * 8);
        kf[f] = *reinterpret_cast<const bf16x8*>(Kp + n * 32 + lg * 8);
    }
    f32x4 s[4][4] = {};
#pragma unroll
    for (int fm = 0; fm < 4; ++fm)
#pragma unroll
        for (int fn = 0; fn < 4; ++fn)
            s[fm][fn] = MFMA(qf[fm], kf[fn], s[fm][fn], 0, 0, 0);

    // ---- softmax (wave-parallel, 16-lane-group reduce) ----
    const float* bh = biasF + head * 2401;
    u16* pl = &plds[wave][0];
#pragma unroll
    for (int fm = 0; fm < 4; ++fm) {
#pragma unroll
        for (int r = 0; r < 4; ++r) {
            const int row = fm * 16 + lg * 4 + r;
            const int brow = row > 48 ? 48 : row;
            float v[4];
#pragma unroll
            for (int fn = 0; fn < 4; ++fn) {
                const int col = fn * 16 + lr;
                const float bval = bh[brow * 49 + (col > 48 ? 48 : col)];
                v[fn] = (col > 48) ? -3.0e38f : (s[fm][fn][r] + bval);
            }
            float mx = fmaxf(fmaxf(v[0], v[1]), fmaxf(v[2], v[3]));
#pragma unroll
            for (int d = 1; d < 16; d <<= 1) mx = fmaxf(mx, __shfl_xor(mx, d));
            float p[4], sum = 0.f;
#pragma unroll
            for (int fn = 0; fn < 4; ++fn) {
                const int col = fn * 16 + lr;
                p[fn] = (col <= 48) ? __expf(v[fn] - mx) : 0.f;
                sum += p[fn];
            }
#pragma unroll
            for (int d = 1; d < 16; d <<= 1) sum += __shfl_xor(sum, d);
            const float rinv = __builtin_amdgcn_rcpf(sum);
#pragma unroll
            for (int fn = 0; fn < 4; ++fn)
                pl[row * 72 + fn * 16 + lr] = f2b(p[fn] * rinv);
        }
    }
    __syncthreads();

    // ---- PV ----
    f32x4 o[4][2] = {};
#pragma unroll
    for (int kc = 0; kc < 2; ++kc) {
        bf16x8 vf[2];
#pragma unroll
        for (int f2 = 0; f2 < 2; ++f2)
            vf[f2] = *reinterpret_cast<const bf16x8*>(vl + (f2 * 16 + lr) * 72 + kc * 32 + lg * 8);
#pragma unroll
        for (int fm = 0; fm < 4; ++fm) {
            const bf16x8 pa = *reinterpret_cast<const bf16x8*>(pl + (fm * 16 + lr) * 72 + kc * 32 + lg * 8);
#pragma unroll
            for (int f2 = 0; f2 < 2; ++f2)
                o[fm][f2] = MFMA(pa, vf[f2], o[fm][f2], 0, 0, 0);
        }
    }

    // ---- window-reverse store ----
    const int b = win >> 10, rem = win & 1023, wy = rem >> 5, wx = rem & 31;
#pragma unroll
    for (int fm = 0; fm < 4; ++fm) {
#pragma unroll
        for (int r = 0; r < 4; ++r) {
            const int tok = fm * 16 + lg * 4 + r;
            if (tok > 48) continue;
            const int y = wy * 7 + tok / 7, xx = wx * 7 + tok % 7;
            const size_t mrow = ((size_t)(b * 224 + y)) * 224 + xx;
#pragma unroll
            for (int f2 = 0; f2 < 2; ++f2)
                outb[mrow * 256 + head * 32 + f2 * 16 + lr] = f2b(o[fm][f2][r]);
        }
    }
}

// ---------------------------------------------------------------------------
// Helpers
// ---------------------------------------------------------------------------
__global__ __launch_bounds__(256)
void cvt_w(const float* __restrict__ qw, const float* __restrict__ pw,
           const float* __restrict__ f1, const float* __restrict__ f2,
           u16* __restrict__ outw)
{
    const int t = blockIdx.x * 256 + threadIdx.x;  // 786432 total
    float v;
    if (t < 196608) v = qw[t];
    else if (t < 262144) v = pw[t - 196608];
    else if (t < 524288) v = f1[t - 262144];
    else v = f2[t - 524288];
    outw[t] = f2b(v);
}

__global__ __launch_bounds__(256)
void bias_pre(const float* __restrict__ btab, const int* __restrict__ relidx,
              float* __restrict__ biasF)
{
    const int t = blockIdx.x * 256 + threadIdx.x;
    if (t >= 19208) return;
    const int head = t / 2401, ij = t % 2401;
    biasF[t] = btab[relidx[ij] * 8 + head];
}

// ---------------------------------------------------------------------------
extern "C" void kernel_launch(void* const* d_in, const int* in_sizes, int n_in,
                              void* d_out, int out_size, void* d_ws, size_t ws_size,
                              hipStream_t stream)
{
    const float* x      = (const float*)d_in[0];
    const float* n1g    = (const float*)d_in[1];
    const float* n1b    = (const float*)d_in[2];
    const float* qkv_w  = (const float*)d_in[3];
    const float* qkv_b  = (const float*)d_in[4];
    const float* btab   = (const float*)d_in[5];
    const float* proj_w = (const float*)d_in[6];
    const float* proj_b = (const float*)d_in[7];
    const float* n2g    = (const float*)d_in[8];
    const float* n2b    = (const float*)d_in[9];
    const float* fc1_w  = (const float*)d_in[10];
    const float* fc1_b  = (const float*)d_in[11];
    const float* fc2_w  = (const float*)d_in[12];
    const float* fc2_b  = (const float*)d_in[13];
    const int*   relidx = (const int*)d_in[14];
    float* out = (float*)d_out;

    // workspace layout:
    //  [0, 1572864)                    : bf16 weights
    //  [1572864, 1649696)              : bias_full f32 (8x49x49)
    //  [1650688, +102760448)           : A region (bf16 token x 256): h / attn_out / h2
    //  [104411136, ...)                : R region: Q|K|V (308.3 MB), reused as MLP hidden
    char* ws = (char*)d_ws;
    u16*   wbf   = (u16*)ws;
    float* biasF = (float*)(ws + 1572864);
    u16*   hbuf  = (u16*)(ws + 1650688);
    u16*   rbuf  = (u16*)(ws + 1650688 + 102760448);
    const size_t r_avail = ws_size - (1650688 + 102760448);

    const u16* Wq  = wbf;
    const u16* Wp  = wbf + 196608;
    const u16* Wf1 = wbf + 262144;
    const u16* Wf2 = wbf + 524288;

    cvt_w<<<3072, 256, 0, stream>>>(qkv_w, proj_w, fc1_w, fc2_w, wbf);
    bias_pre<<<76, 256, 0, stream>>>(btab, relidx, biasF);
    layernorm_k<<<50176, 256, 0, stream>>>(x, n1g, n1b, hbuf);

    // QKV projection: M=200704 (784 m-tiles), N=768, K=256
    gemm256<0><<<784 * 3, 512, 0, stream>>>(hbuf, Wq, qkv_b, 3, 256, rbuf, nullptr, nullptr);
    // window attention
    attn_win<<<8192, 256, 0, stream>>>(rbuf, biasF, hbuf);
    // proj + residual -> d_out (x1)
    gemm256<1><<<784, 512, 0, stream>>>(hbuf, Wp, proj_b, 1, 256, nullptr, out, x);
    // LN2: d_out -> h2
    layernorm_k<<<50176, 256, 0, stream>>>(out, n2g, n2b, hbuf);

    // MLP, chunked so hidden (bf16, M x 1024) fits in R region
    long rows_cap = (long)(r_avail / 2048);
    long rows_per = (rows_cap / 256) * 256;
    if (rows_per > TOKENS) rows_per = TOKENS;
    if (rows_per < 256) rows_per = 256;
    for (long r0 = 0; r0 < TOKENS; r0 += rows_per) {
        const long rows = (TOKENS - r0 < rows_per) ? (TOKENS - r0) : rows_per;
        gemm256<2><<<(int)((rows / 256) * 4), 512, 0, stream>>>(
            hbuf + r0 * 256, Wf1, fc1_b, 4, 256, rbuf, nullptr, nullptr);
        gemm256<3><<<(int)(rows / 256), 512, 0, stream>>>(
            rbuf, Wf2, fc2_b, 1, 1024, nullptr, out + r0 * 256, nullptr);
    }
}